// Round 10
// baseline (116.050 us; speedup 1.0000x reference)
//
#include <hip/hip_runtime.h>
#include <math.h>

// SegmentCausalCrossAttentionFlex on MI355X (gfx950)
// B=2, LQ=4096, LK=512, Q_DIM=KV_DIM=D_ATTN=1024, H=16, HD=64, LOOKBACK=4
// R10: BARRIER-FREE 1-wave GEMM core. Block = 64 thr = 1 wave, tile 64x64,
// BK=32, acc[4][4]; wave stages its own tiles (8 gload_lds, 2-buf 16KB LDS),
// waits only its own vmcnt(8). Zero s_barrier in the GEMM kernels.
// 10 blocks/CU = 10 independent pipelines; no cross-wave convoys.

typedef unsigned short u16;
typedef __attribute__((ext_vector_type(8))) short bhalf8;   // 8 x bf16 (MFMA A/B frag)
typedef __attribute__((ext_vector_type(4))) float fvec4;    // MFMA C/D frag

#define MFMA(a, b, c) __builtin_amdgcn_mfma_f32_16x16x32_bf16((a), (b), (c), 0, 0, 0)

__device__ __forceinline__ u16 f2bf(float f) {
  unsigned u = __float_as_uint(f);
  u += 0x7fffu + ((u >> 16) & 1u);      // round-to-nearest-even
  return (u16)(u >> 16);
}
__device__ __forceinline__ float bf2f(u16 h) {
  return __uint_as_float(((unsigned)h) << 16);
}

// ---------------------------------------------------------------------------
// Fused preprocessing (unchanged from R3).
__global__ __launch_bounds__(256) void prep_kernel(
    const float* __restrict__ Wq, const float* __restrict__ Wkv,
    const float* __restrict__ Wo, u16* __restrict__ WqT,
    u16* __restrict__ WkvT, u16* __restrict__ WoT,
    const float* __restrict__ q, u16* __restrict__ qb,
    const float* __restrict__ kv, u16* __restrict__ kvb,
    float2* __restrict__ csT) {
  const int bid = blockIdx.x;
  if (bid < 4096) {
    __shared__ float tile[32][33];
    const float* W;
    u16* Wt;
    int N, t;
    if (bid < 1024)      { W = Wq;  Wt = WqT;  N = 1024; t = bid; }
    else if (bid < 3072) { W = Wkv; Wt = WkvT; N = 2048; t = bid - 1024; }
    else                 { W = Wo;  Wt = WoT;  N = 1024; t = bid - 3072; }
    const int sh = (N >> 11) + 5;               // 1024->5, 2048->6
    const int n0 = (t & ((1 << sh) - 1)) << 5;
    const int k0 = (t >> sh) << 5;
    const int tx = threadIdx.x & 31, ty = threadIdx.x >> 5;
#pragma unroll
    for (int i = 0; i < 32; i += 8)
      tile[ty + i][tx] = W[(size_t)(k0 + ty + i) * N + n0 + tx];
    __syncthreads();
#pragma unroll
    for (int i = 0; i < 32; i += 8)
      Wt[(size_t)(n0 + ty + i) * 1024 + k0 + tx] = f2bf(tile[tx][ty + i]);
    return;
  }
  const int NQ4 = 2097152, NKV4 = 262144, NR = 131072;
  const int stride = 2048 * 256;
  for (int u = (bid - 4096) * 256 + threadIdx.x; u < NQ4 + NKV4 + NR; u += stride) {
    if (u < NQ4) {
      const float4 v = ((const float4*)q)[u];
      ushort4 o;
      o.x = f2bf(v.x); o.y = f2bf(v.y); o.z = f2bf(v.z); o.w = f2bf(v.w);
      ((ushort4*)qb)[u] = o;
    } else if (u < NQ4 + NKV4) {
      const int i = u - NQ4;
      const float4 v = ((const float4*)kv)[i];
      ushort4 o;
      o.x = f2bf(v.x); o.y = f2bf(v.y); o.z = f2bf(v.z); o.w = f2bf(v.w);
      ((ushort4*)kvb)[i] = o;
    } else {
      const int i = u - NQ4 - NKV4;
      const int pos = i >> 5, j = i & 31;
      const float invf = expf(-(float)j * 0.28782313662425572f);  // ln(10000)/32
      float s, c;
      sincosf((float)pos * invf, &s, &c);
      csT[i] = make_float2(c, s);
    }
  }
}

// ---------------------------------------------------------------------------
// Barrier-free 64x64 GEMM tile core (one wave per block).
// acc[4][4] frags of 16x16 (mfma 16x16x32), BK=32, K=1024 = 32 steps.
// Per step: issue 8 gload_lds for tile t+1 (own loads) -> s_waitcnt vmcnt(8)
// (tile t landed; only the 8 newest outstanding) -> 8 ds_read_b128 ->
// 16 MFMA. No s_barrier anywhere (wave-synchronous LDS).
// WAR safety on 2 buffers: step t+1 stages into buf[t&1]; step t's ds_reads
// delivered to VGPRs (compiler lgkmcnt before the MFMAs) before the stage
// instructions issue in program order.
// 16B-chunk XOR swizzle slot = g ^ ((row>>1)&3), same K-bijection both
// operands (MFMA contraction invariant, verified since R1).
__device__ __forceinline__ void gemm_core_1w(
    const u16* __restrict__ A, const u16* __restrict__ Bt,
    int m0, int n0, fvec4 acc[4][4], u16* As, u16* Bs) {
  const int lane = threadIdx.x & 63;

  int off[4];                       // frag read offsets (A and B identical)
#pragma unroll
  for (int i = 0; i < 4; ++i) {
    const int rr = i * 16 + (lane & 15);
    off[i] = rr * 32 + (((lane >> 4) ^ ((rr >> 1) & 3)) << 3);
  }
  // staging: tile = 256 16B-chunks per operand; lane stages chunks j*64+lane.
  const u16* ag[4];
  const u16* bg[4];
#pragma unroll
  for (int j = 0; j < 4; ++j) {
    const int c = j * 64 + lane;
    const int r = c >> 2, g = (c & 3) ^ ((r >> 1) & 3);
    ag[j] = A + (size_t)(m0 + r) * 1024 + g * 8;
    bg[j] = Bt + (size_t)(n0 + r) * 1024 + g * 8;
  }
  const int l8 = lane * 8;

#define STAGE1W(buf, kk)                                                     \
  do {                                                                       \
    _Pragma("unroll") for (int j = 0; j < 4; ++j)                            \
        __builtin_amdgcn_global_load_lds(                                    \
            (__attribute__((address_space(1))) void*)(ag[j] + (kk)),         \
            (__attribute__((address_space(3))) void*)(As + (buf) * 2048 +    \
                                                      j * 512 + l8),         \
            16, 0, 0);                                                       \
    _Pragma("unroll") for (int j = 0; j < 4; ++j)                            \
        __builtin_amdgcn_global_load_lds(                                    \
            (__attribute__((address_space(1))) void*)(bg[j] + (kk)),         \
            (__attribute__((address_space(3))) void*)(Bs + (buf) * 2048 +    \
                                                      j * 512 + l8),         \
            16, 0, 0);                                                       \
  } while (0)

  STAGE1W(0, 0);                    // prologue: stage tile 0
#pragma unroll
  for (int t = 0; t < 32; ++t) {
    if (t < 31) {
      STAGE1W((t + 1) & 1, (t + 1) * 32);
      asm volatile("s_waitcnt vmcnt(8)" ::: "memory");   // tile t landed
    } else {
      asm volatile("s_waitcnt vmcnt(0)" ::: "memory");   // drain tail
    }
    const int co = (t & 1) * 2048;
    bhalf8 af[4], bfv[4];
#pragma unroll
    for (int i = 0; i < 4; ++i) af[i] = *(const bhalf8*)(As + co + off[i]);
#pragma unroll
    for (int i = 0; i < 4; ++i) bfv[i] = *(const bhalf8*)(Bs + co + off[i]);
    __builtin_amdgcn_s_setprio(1);
#pragma unroll
    for (int mi = 0; mi < 4; ++mi)
#pragma unroll
      for (int ni = 0; ni < 4; ++ni)
        acc[mi][ni] = MFMA(af[mi], bfv[ni], acc[mi][ni]);
    __builtin_amdgcn_s_setprio(0);
  }
#undef STAGE1W
}

#define GEMM_PROLOGUE()                                              \
  __shared__ __align__(16) u16 As[2 * 2048];                         \
  __shared__ __align__(16) u16 Bs[2 * 2048];                         \
  fvec4 acc[4][4];                                                   \
  _Pragma("unroll") for (int i = 0; i < 4; ++i)                      \
      _Pragma("unroll") for (int j = 0; j < 4; ++j)                  \
          acc[i][j] = (fvec4){0.f, 0.f, 0.f, 0.f};

// ---------------------------------------------------------------------------
// Fused GEMM1+GEMM2, 2560 wgs x 64 thr (8 XCD chunks of 320; kv tiles
// interleaved every 5th: 320 = 256 qh + 64 kv per XCD).
// qh role:  qh = bf16( RoPE(q @ Wq) * 0.125 )  M=8192 N=1024 (128x16 tiles)
// kv role:  kvl = kv @ Wkv (16x32 tiles); n0<1024 -> kh (RoPE), else vh.
// Each 64-col tile spans exactly one head (n0 % 64 == 0).
__global__ __launch_bounds__(64) void gemm12_kernel(
    const u16* __restrict__ qA, const u16* __restrict__ WqT,
    const u16* __restrict__ kvA, const u16* __restrict__ WkvT,
    u16* __restrict__ qh, u16* __restrict__ kh, u16* __restrict__ vh,
    const int* __restrict__ qpos, const int* __restrict__ kpos,
    const float2* __restrict__ csT) {
  GEMM_PROLOGUE();
  const int swz = ((blockIdx.x & 7) * 320) + (blockIdx.x >> 3);  // bijective
  const int q5 = swz / 5, r5 = swz - q5 * 5;
  const bool isQ = (r5 < 4);
  const int lane = threadIdx.x & 63;

  const u16 *Aop, *Bop;
  int m0, n0;
  if (isQ) {
    const int id = q5 * 4 + r5;                    // 0..2047
    Aop = qA; Bop = WqT;
    m0 = (id >> 4) * 64; n0 = (id & 15) * 64;
  } else {
    const int id = q5;                             // 0..511
    Aop = kvA; Bop = WkvT;
    m0 = (id >> 5) * 64; n0 = (id & 31) * 64;
  }
  gemm_core_1w(Aop, Bop, m0, n0, acc, As, Bs);

  if (isQ) {
#pragma unroll
    for (int mi = 0; mi < 4; ++mi) {
#pragma unroll
      for (int r = 0; r < 4; ++r) {
        const int rowg = m0 + mi * 16 + (lane >> 4) * 4 + r;
        int pos = qpos[rowg];
        pos = pos < 0 ? 0 : (pos > 4095 ? 4095 : pos);
#pragma unroll
        for (int ni = 0; ni < 2; ++ni) {
          const int j = ni * 16 + (lane & 15);
          const float2 cs = csT[pos * 32 + j];
          const float x1 = acc[mi][ni][r], x2 = acc[mi][ni + 2][r];
          const int colg = n0 + ni * 16 + (lane & 15);
          qh[(size_t)rowg * 1024 + colg]      = f2bf((x1 * cs.x - x2 * cs.y) * 0.125f);
          qh[(size_t)rowg * 1024 + colg + 32] = f2bf((x2 * cs.x + x1 * cs.y) * 0.125f);
        }
      }
    }
  } else {
    const bool isK = n0 < 1024;
#pragma unroll
    for (int mi = 0; mi < 4; ++mi) {
#pragma unroll
      for (int r = 0; r < 4; ++r) {
        const int rowg = m0 + mi * 16 + (lane >> 4) * 4 + r;   // 0..1023
        if (isK) {
          int pos = kpos[rowg & 511];
          pos = pos < 0 ? 0 : (pos > 4095 ? 4095 : pos);
#pragma unroll
          for (int ni = 0; ni < 2; ++ni) {
            const int j = ni * 16 + (lane & 15);
            const float2 cs = csT[pos * 32 + j];
            const float x1 = acc[mi][ni][r], x2 = acc[mi][ni + 2][r];
            const int colg = n0 + ni * 16 + (lane & 15);
            kh[(size_t)rowg * 1024 + colg]      = f2bf(x1 * cs.x - x2 * cs.y);
            kh[(size_t)rowg * 1024 + colg + 32] = f2bf(x2 * cs.x + x1 * cs.y);
          }
        } else {
#pragma unroll
          for (int ni = 0; ni < 4; ++ni) {
            const int colg = n0 + ni * 16 + (lane & 15);
            vh[(size_t)rowg * 1024 + colg - 1024] = f2bf(acc[mi][ni][r]);
          }
        }
      }
    }
  }
}

// ---------------------------------------------------------------------------
// GEMM3: out_f32 = ctx @ Wo   M=8192 N=1024, 2048 wgs x 64 thr
__global__ __launch_bounds__(64) void gemm_out_kernel(
    const u16* __restrict__ A, const u16* __restrict__ Bt,
    float* __restrict__ out) {
  GEMM_PROLOGUE();
  const int swz = ((blockIdx.x & 7) << 8) + (blockIdx.x >> 3);  // 2048 = 8*256
  const int m0 = (swz >> 4) * 64, n0 = (swz & 15) * 64;
  gemm_core_1w(A, Bt, m0, n0, acc, As, Bs);
  const int lane = threadIdx.x & 63;
#pragma unroll
  for (int mi = 0; mi < 4; ++mi) {
#pragma unroll
    for (int r = 0; r < 4; ++r) {
      const int rowg = m0 + mi * 16 + (lane >> 4) * 4 + r;
#pragma unroll
      for (int ni = 0; ni < 4; ++ni) {
        const int colg = n0 + ni * 16 + (lane & 15);
        out[(size_t)rowg * 1024 + colg] = acc[mi][ni][r];
      }
    }
  }
}

// ---------------------------------------------------------------------------
// Sparse attention (unchanged): k in [max(seg-4,0), seg] (<=5 keys).
__global__ __launch_bounds__(256) void attn_kernel(
    const u16* __restrict__ qh, const u16* __restrict__ kh,
    const u16* __restrict__ vh, const int* __restrict__ seg_id,
    u16* __restrict__ ctx) {
  const int lane = threadIdx.x & 63;
  const int row = (blockIdx.x * 256 + threadIdx.x) >> 6;   // 0..8191
  const int b = row >> 12;
  const int sg = seg_id[row];
  const int kmin = sg > 4 ? sg - 4 : 0;

  const u16* qp = qh + (size_t)row * 1024 + lane * 16;
  const bhalf8 qa = *(const bhalf8*)qp;
  const bhalf8 qb = *(const bhalf8*)(qp + 8);
  float qv[16];
#pragma unroll
  for (int e = 0; e < 8; ++e) {
    qv[e] = bf2f((u16)qa[e]);
    qv[8 + e] = bf2f((u16)qb[e]);
  }

  float sc[5];
  float mx = -3.0e38f;
#pragma unroll
  for (int t = 0; t < 5; ++t) {
    const int k = kmin + t;                      // always in [0,511]
    const u16* kp = kh + (size_t)((b << 9) + k) * 1024 + lane * 16;
    const bhalf8 ka = *(const bhalf8*)kp;
    const bhalf8 kb = *(const bhalf8*)(kp + 8);
    float d = 0.f;
#pragma unroll
    for (int e = 0; e < 8; ++e)
      d += qv[e] * bf2f((u16)ka[e]) + qv[8 + e] * bf2f((u16)kb[e]);
    d += __shfl_xor(d, 1);
    d += __shfl_xor(d, 2);                       // sum over 4 lanes of this head
    sc[t] = (k <= sg) ? d : -3.0e38f;
    mx = fmaxf(mx, sc[t]);
  }

  float den = 0.f;
  float o[16];
#pragma unroll
  for (int e = 0; e < 16; ++e) o[e] = 0.f;
#pragma unroll
  for (int t = 0; t < 5; ++t) {
    const float p = __expf(sc[t] - mx);          // masked -> exp(-huge) = 0
    den += p;
    const int k = kmin + t;
    const u16* vp = vh + (size_t)((b << 9) + k) * 1024 + lane * 16;
    const bhalf8 va = *(const bhalf8*)vp;
    const bhalf8 vb = *(const bhalf8*)(vp + 8);
#pragma unroll
    for (int e = 0; e < 8; ++e) {
      o[e] += p * bf2f((u16)va[e]);
      o[8 + e] += p * bf2f((u16)vb[e]);
    }
  }
  const float inv = 1.f / den;
  bhalf8 oa, ob;
#pragma unroll
  for (int e = 0; e < 8; ++e) {
    oa[e] = (short)f2bf(o[e] * inv);
    ob[e] = (short)f2bf(o[8 + e] * inv);
  }
  u16* cp = ctx + (size_t)row * 1024 + lane * 16;
  *(bhalf8*)cp = oa;
  *(bhalf8*)(cp + 8) = ob;
}

// ---------------------------------------------------------------------------
extern "C" void kernel_launch(void* const* d_in, const int* in_sizes, int n_in,
                              void* d_out, int out_size, void* d_ws, size_t ws_size,
                              hipStream_t stream) {
  const float* q   = (const float*)d_in[0];
  const float* kv  = (const float*)d_in[1];
  const int* qpos  = (const int*)d_in[2];
  const int* kpos  = (const int*)d_in[3];
  const int* seg   = (const int*)d_in[4];
  const float* Wq  = (const float*)d_in[5];
  const float* Wkv = (const float*)d_in[6];
  const float* Wo  = (const float*)d_in[7];
  float* out = (float*)d_out;

  // workspace carve-up (~66 MB total)
  char* w = (char*)d_ws;
  u16* qb    = (u16*)w; w += (size_t)8192 * 1024 * 2;
  u16* kvb   = (u16*)w; w += (size_t)1024 * 1024 * 2;
  u16* WqT   = (u16*)w; w += (size_t)1024 * 1024 * 2;
  u16* WkvT  = (u16*)w; w += (size_t)2048 * 1024 * 2;
  u16* WoT   = (u16*)w; w += (size_t)1024 * 1024 * 2;
  u16* qhB   = (u16*)w; w += (size_t)8192 * 1024 * 2;
  u16* khB   = (u16*)w; w += (size_t)1024 * 1024 * 2;
  u16* vhB   = (u16*)w; w += (size_t)1024 * 1024 * 2;
  u16* ctxB  = (u16*)w; w += (size_t)8192 * 1024 * 2;
  float2* csT = (float2*)w; w += (size_t)4096 * 32 * 8;

  prep_kernel<<<6144, 256, 0, stream>>>(Wq, Wkv, Wo, WqT, WkvT, WoT,
                                        q, qb, kv, kvb, csT);
  gemm12_kernel<<<2560, 64, 0, stream>>>(qb, WqT, kvb, WkvT,
                                         qhB, khB, vhB, qpos, kpos, csT);
  attn_kernel<<<2048, 256, 0, stream>>>(qhB, khB, vhB, seg, ctxB);
  gemm_out_kernel<<<2048, 64, 0, stream>>>(ctxB, WoT, out);
}